// Round 11
// baseline (182.995 us; speedup 1.0000x reference)
//
#include <hip/hip_runtime.h>
#include <hip/hip_bf16.h>
#include <stdint.h>
#include <type_traits>

// Problem constants
#define B_    2
#define HW_   4096
#define NTGT_ 4096
#define C_    512
#define H_    8
#define KNN_  32
#define DH_   64
#define M_    (B_ * HW_)

typedef unsigned short ushort_t;
typedef _Float16 f16x8 __attribute__((ext_vector_type(8)));
typedef __fp16 hf2 __attribute__((ext_vector_type(2)));
typedef float floatx4 __attribute__((ext_vector_type(4)));

// ---- fp16 helpers (intermediates are IEEE fp16: more mantissa than bf16)
__device__ __forceinline__ uint32_t pkh(float x, float y) {
    union { hf2 h; uint32_t u; } c;
    c.h = __builtin_amdgcn_cvt_pkrtz(x, y);   // v_cvt_pkrtz_f16_f32
    return c.u;
}
__device__ __forceinline__ ushort_t f2h(float f) {
    return (ushort_t)(pkh(f, 0.f) & 0xffffu);
}
__device__ __forceinline__ float h2f(ushort_t u) {
    union { ushort_t s; __fp16 h; } x;
    x.s = u;
    return (float)x.h;                         // v_cvt_f32_f16
}
// bf16 round-to-nearest (final-output defensive path only)
__device__ __forceinline__ ushort_t f2b(float f) {
    union { float f; uint32_t i; } x;
    x.f = f;
    uint32_t r = x.i + 0x7fffu + ((x.i >> 16) & 1u);
    return (ushort_t)(r >> 16);
}
// 2-way fp16 dot with f32 accumulate: v_dot2_f32_f16
__device__ __forceinline__ float dot2acc(uint32_t a, uint32_t b, float c) {
#if __has_builtin(__builtin_amdgcn_fdot2)
    union { uint32_t u; hf2 h; } xa, xb;
    xa.u = a; xb.u = b;
    return __builtin_amdgcn_fdot2(xa.h, xb.h, c, false);
#else
    c = fmaf(h2f((ushort_t)(a & 0xffffu)), h2f((ushort_t)(b & 0xffffu)), c);
    return fmaf(h2f((ushort_t)(a >> 16)), h2f((ushort_t)(b >> 16)), c);
#endif
}
__device__ __forceinline__ uint4 pack8(const float4& a, const float4& b) {
    return make_uint4(pkh(a.x, a.y), pkh(a.z, a.w), pkh(b.x, b.y), pkh(b.z, b.w));
}
// Async global->LDS, 16B per lane. LDS dest = wave-uniform base + lane*16B;
// global source is per-lane. vmcnt-counted; __syncthreads() drains it.
__device__ __forceinline__ void gl16(const ushort_t* g, ushort_t* l) {
    __builtin_amdgcn_global_load_lds(
        (__attribute__((address_space(1))) void*)(g),
        (__attribute__((address_space(3))) void*)(l), 16, 0, 0);
}

// ---------------------------------------------------------------------------
// Elementwise fp32 -> fp16 convert for src/tgt (enables gload_lds GEMM-A).
// grid (4096, 2) x 256: exactly one float4 per thread.
// ---------------------------------------------------------------------------
__global__ __launch_bounds__(256) void cvt_f32_f16_2(
    const float* __restrict__ A0, const float* __restrict__ A1,
    ushort_t* __restrict__ O0, ushort_t* __restrict__ O1) {
    const float* A = blockIdx.y ? A1 : A0;
    ushort_t* O = blockIdx.y ? O1 : O0;
    const size_t i = ((size_t)blockIdx.x * 256 + threadIdx.x) * 4;
    float4 v = *(const float4*)&A[i];
    *(uint2*)&O[i] = make_uint2(pkh(v.x, v.y), pkh(v.z, v.w));
}

// ---------------------------------------------------------------------------
// Out-of-place transpose+convert: T_fp16[n][k] = W_fp32[k][n], 4 matrices.
// No input mutation. grid (16,16,4).
// ---------------------------------------------------------------------------
__global__ __launch_bounds__(256) void transpose_cvt4(
    const float* __restrict__ W0, const float* __restrict__ W1,
    const float* __restrict__ W2, const float* __restrict__ W3,
    ushort_t* __restrict__ T0, ushort_t* __restrict__ T1,
    ushort_t* __restrict__ T2, ushort_t* __restrict__ T3) {
    __shared__ float tile[32][33];

    const float* W = (blockIdx.z == 0) ? W0 : (blockIdx.z == 1) ? W1
                     : (blockIdx.z == 2) ? W2 : W3;
    ushort_t* T = (blockIdx.z == 0) ? T0 : (blockIdx.z == 1) ? T1
                  : (blockIdx.z == 2) ? T2 : T3;

    const int k0 = blockIdx.x * 32;
    const int n0 = blockIdx.y * 32;
    const int t = threadIdx.x;
    const int r = t >> 3;
    const int c0 = (t & 7) * 4;

    float4 d = *(const float4*)&W[(size_t)(k0 + r) * 512 + n0 + c0];
    tile[r][c0 + 0] = d.x; tile[r][c0 + 1] = d.y;
    tile[r][c0 + 2] = d.z; tile[r][c0 + 3] = d.w;
    __syncthreads();

    uint2 o;
    o.x = pkh(tile[c0 + 0][r], tile[c0 + 1][r]);
    o.y = pkh(tile[c0 + 2][r], tile[c0 + 3][r]);
    *(uint2*)&T[(size_t)(n0 + r) * 512 + k0 + c0] = o;
}

// ---------------------------------------------------------------------------
// IN-PLACE fp32 transpose fallback (if ws can't hold fp16 weights).
// ---------------------------------------------------------------------------
__global__ __launch_bounds__(256) void transpose_inplace4_f32(
    float* W0, float* W1, float* W2, float* W3) {
    __shared__ float ta[32][33];
    __shared__ float tb[32][33];

    float* W = (blockIdx.y == 0) ? W0 : (blockIdx.y == 1) ? W1
               : (blockIdx.y == 2) ? W2 : W3;

    int p = blockIdx.x;
    int i = 0, acc = 0;
    while (acc + (16 - i) <= p) { acc += 16 - i; ++i; }
    const int j = i + (p - acc);

    const int t = threadIdx.x;
    const int r = t >> 3;
    const int c0 = (t & 7) * 4;

    {
        float4 d = *(const float4*)&W[(size_t)(i * 32 + r) * 512 + j * 32 + c0];
        ta[r][c0 + 0] = d.x; ta[r][c0 + 1] = d.y;
        ta[r][c0 + 2] = d.z; ta[r][c0 + 3] = d.w;
    }
    if (i != j) {
        float4 d = *(const float4*)&W[(size_t)(j * 32 + r) * 512 + i * 32 + c0];
        tb[r][c0 + 0] = d.x; tb[r][c0 + 1] = d.y;
        tb[r][c0 + 2] = d.z; tb[r][c0 + 3] = d.w;
    }
    __syncthreads();

    *(float4*)&W[(size_t)(j * 32 + r) * 512 + i * 32 + c0] =
        make_float4(ta[c0 + 0][r], ta[c0 + 1][r], ta[c0 + 2][r], ta[c0 + 3][r]);
    if (i != j)
        *(float4*)&W[(size_t)(i * 32 + r) * 512 + j * 32 + c0] =
            make_float4(tb[c0 + 0][r], tb[c0 + 1][r], tb[c0 + 2][r], tb[c0 + 3][r]);
}

// ---------------------------------------------------------------------------
// NEW fast GEMM body: fp16 A/B, staged ENTIRELY by global_load_lds width=16
// (Common-mistake #1 / m97 recipe: 517->874 TF from this alone). Linear
// unpadded LDS [128][32] (gload_lds requires contiguous lane-order dest;
// 64B rows -> ~4-way ds_read conflict, same as m97 at 874 TF). Per wave per
// K-step: 4 gload_lds + 8 ds_read_b128 + 16 MFMA, 2 barriers (the barrier's
// vmcnt(0) drain IS the staging sync).
// ---------------------------------------------------------------------------
template <typename OT, int BN, bool OBF16>
__device__ __forceinline__ void gemm_body_gl(const ushort_t* __restrict__ A,
                                             const ushort_t* __restrict__ Wt,
                                             const float* __restrict__ bias,
                                             OT* __restrict__ O,
                                             int bm, int bn) {
    constexpr int NJ = BN / 32;
    __shared__ ushort_t Asf[128 * 32];   // [m][k] fp16, linear
    __shared__ ushort_t Bsf[BN * 32];    // [n][k] fp16, linear

    const int t = threadIdx.x;
    const int lane = t & 63;
    const int wv = t >> 6;
    const int wr = (wv >> 1) * 64;
    const int wc = (wv & 1) * (BN / 2);
    const int r16 = lane & 15;
    const int quad = lane >> 4;

    // gload_lds lane map: wave wv chunk covers 16 rows; lane l -> row
    // wv*16 + (l>>2), col (l&3)*8 (16B). LDS dest base wave-uniform.
    const int srow = wv * 16 + (lane >> 2);
    const int scol = (lane & 3) * 8;
    const ushort_t* ag0 = &A[(size_t)(bm + srow) * 512 + scol];
    const ushort_t* ag1 = &A[(size_t)(bm + 64 + srow) * 512 + scol];
    const ushort_t* bg0 = &Wt[(size_t)(bn + srow) * 512 + scol];
    const ushort_t* bg1 = &Wt[(size_t)(bn + 64 + srow) * 512 + scol];
    ushort_t* al0 = &Asf[wv * 512];
    ushort_t* al1 = &Asf[2048 + wv * 512];
    ushort_t* bl0 = &Bsf[wv * 512];
    ushort_t* bl1 = &Bsf[2048 + wv * 512];

    floatx4 acc[4][NJ] = {};

    for (int kt = 0; kt < 512; kt += 32) {
        gl16(ag0 + kt, al0);
        gl16(ag1 + kt, al1);
        gl16(bg0 + kt, bl0);
        if constexpr (BN == 128) gl16(bg1 + kt, bl1);
        __syncthreads();  // vmcnt(0) drain: tile staged & visible

        f16x8 af[4], bf[NJ];
#pragma unroll
        for (int i = 0; i < 4; ++i)
            af[i] = *(const f16x8*)&Asf[(wr + i * 16 + r16) * 32 + quad * 8];
#pragma unroll
        for (int j = 0; j < NJ; ++j)
            bf[j] = *(const f16x8*)&Bsf[(wc + j * 16 + r16) * 32 + quad * 8];
#pragma unroll
        for (int i = 0; i < 4; ++i)
#pragma unroll
            for (int j = 0; j < NJ; ++j)
                acc[i][j] = __builtin_amdgcn_mfma_f32_16x16x32_f16(
                    af[i], bf[j], acc[i][j], 0, 0, 0);
        __syncthreads();  // frag reads done before next stage overwrites
    }

    // D layout: col=lane&15, row=quad*4+reg [m89]
#pragma unroll
    for (int j = 0; j < NJ; ++j) {
        const int col = bn + wc + j * 16 + r16;
        const float bj = bias[col];
#pragma unroll
        for (int i = 0; i < 4; ++i) {
            const int row = bm + wr + i * 16 + quad * 4;
#pragma unroll
            for (int r = 0; r < 4; ++r) {
                float v = acc[i][j][r] + bj;
                if constexpr (std::is_same<OT, float>::value)
                    O[(size_t)(row + r) * 512 + col] = v;
                else if constexpr (OBF16)
                    O[(size_t)(row + r) * 512 + col] = f2b(v);
                else
                    O[(size_t)(row + r) * 512 + col] = f2h(v);
            }
        }
    }
}

// ---------------------------------------------------------------------------
// OLD reg-staging GEMM body (R4-proven) — kept for fallback tiers where
// A or B is fp32 (gload_lds cannot convert).
// ---------------------------------------------------------------------------
template <typename AT, typename BT, typename OT, int BN, bool OBF16>
__device__ __forceinline__ void gemm_body(const AT* __restrict__ A,
                                          const BT* __restrict__ Wt,
                                          const float* __restrict__ bias,
                                          OT* __restrict__ O,
                                          int bm, int bn) {
    constexpr int NJ = BN / 32;          // MFMAs in n per wave
    __shared__ ushort_t As[128][40];     // [m][k] fp16, 80B stride
    __shared__ ushort_t Bs[BN][40];      // [n][k] fp16

    const int t = threadIdx.x;
    const int lr = t >> 2;        // 0..63
    const int lc = (t & 3) * 8;   // 0,8,16,24

    const int lane = t & 63;
    const int wv = t >> 6;
    const int wr = (wv >> 1) * 64;
    const int wc = (wv & 1) * (BN / 2);
    const int r16 = lane & 15;
    const int quad = lane >> 4;

    floatx4 acc[4][NJ] = {};

    float4 fa0, fa1, fa2, fa3, fb0, fb1, fb2, fb3;
    uint4 ua0, ua1, ub0, ub1;

    // prefetch kt = 0
    if constexpr (std::is_same<AT, float>::value) {
        const float* p0 = &A[(size_t)(bm + lr) * 512 + lc];
        const float* p1 = &A[(size_t)(bm + lr + 64) * 512 + lc];
        fa0 = *(const float4*)p0; fa1 = *(const float4*)(p0 + 4);
        fa2 = *(const float4*)p1; fa3 = *(const float4*)(p1 + 4);
    } else {
        ua0 = *(const uint4*)&A[(size_t)(bm + lr) * 512 + lc];
        ua1 = *(const uint4*)&A[(size_t)(bm + lr + 64) * 512 + lc];
    }
    if constexpr (std::is_same<BT, float>::value) {
        const float* p0 = &Wt[(size_t)(bn + lr) * 512 + lc];
        fb0 = *(const float4*)p0; fb1 = *(const float4*)(p0 + 4);
        if constexpr (BN == 128) {
            const float* p1 = &Wt[(size_t)(bn + lr + 64) * 512 + lc];
            fb2 = *(const float4*)p1; fb3 = *(const float4*)(p1 + 4);
        }
    } else {
        ub0 = *(const uint4*)&Wt[(size_t)(bn + lr) * 512 + lc];
        if constexpr (BN == 128)
            ub1 = *(const uint4*)&Wt[(size_t)(bn + lr + 64) * 512 + lc];
    }

    for (int kt = 0; kt < 512; kt += 32) {
        __syncthreads();  // prior iteration's fragment reads complete
        if constexpr (std::is_same<AT, float>::value) {
            *(uint4*)&As[lr][lc] = pack8(fa0, fa1);
            *(uint4*)&As[lr + 64][lc] = pack8(fa2, fa3);
        } else {
            *(uint4*)&As[lr][lc] = ua0;
            *(uint4*)&As[lr + 64][lc] = ua1;
        }
        if constexpr (std::is_same<BT, float>::value) {
            *(uint4*)&Bs[lr][lc] = pack8(fb0, fb1);
            if constexpr (BN == 128) *(uint4*)&Bs[lr + 64][lc] = pack8(fb2, fb3);
        } else {
            *(uint4*)&Bs[lr][lc] = ub0;
            if constexpr (BN == 128) *(uint4*)&Bs[lr + 64][lc] = ub1;
        }
        __syncthreads();

        if (kt + 32 < 512) {  // issue next-tile loads; wait lands at publish
            const int k2 = kt + 32;
            if constexpr (std::is_same<AT, float>::value) {
                const float* p0 = &A[(size_t)(bm + lr) * 512 + k2 + lc];
                const float* p1 = &A[(size_t)(bm + lr + 64) * 512 + k2 + lc];
                fa0 = *(const float4*)p0; fa1 = *(const float4*)(p0 + 4);
                fa2 = *(const float4*)p1; fa3 = *(const float4*)(p1 + 4);
            } else {
                ua0 = *(const uint4*)&A[(size_t)(bm + lr) * 512 + k2 + lc];
                ua1 = *(const uint4*)&A[(size_t)(bm + lr + 64) * 512 + k2 + lc];
            }
            if constexpr (std::is_same<BT, float>::value) {
                const float* p0 = &Wt[(size_t)(bn + lr) * 512 + k2 + lc];
                fb0 = *(const float4*)p0; fb1 = *(const float4*)(p0 + 4);
                if constexpr (BN == 128) {
                    const float* p1 = &Wt[(size_t)(bn + lr + 64) * 512 + k2 + lc];
                    fb2 = *(const float4*)p1; fb3 = *(const float4*)(p1 + 4);
                }
            } else {
                ub0 = *(const uint4*)&Wt[(size_t)(bn + lr) * 512 + k2 + lc];
                if constexpr (BN == 128)
                    ub1 = *(const uint4*)&Wt[(size_t)(bn + lr + 64) * 512 + k2 + lc];
            }
        }

        f16x8 af[4], bf[NJ];
#pragma unroll
        for (int i = 0; i < 4; ++i)
            af[i] = *(const f16x8*)&As[wr + i * 16 + r16][quad * 8];
#pragma unroll
        for (int j = 0; j < NJ; ++j)
            bf[j] = *(const f16x8*)&Bs[wc + j * 16 + r16][quad * 8];
#pragma unroll
        for (int i = 0; i < 4; ++i)
#pragma unroll
            for (int j = 0; j < NJ; ++j)
                acc[i][j] = __builtin_amdgcn_mfma_f32_16x16x32_f16(
                    af[i], bf[j], acc[i][j], 0, 0, 0);
    }

    // D layout: col=lane&15, row=quad*4+reg [m89]
#pragma unroll
    for (int j = 0; j < NJ; ++j) {
        const int col = bn + wc + j * 16 + r16;
        const float bj = bias[col];
#pragma unroll
        for (int i = 0; i < 4; ++i) {
            const int row = bm + wr + i * 16 + quad * 4;
#pragma unroll
            for (int r = 0; r < 4; ++r) {
                float v = acc[i][j][r] + bj;
                if constexpr (std::is_same<OT, float>::value)
                    O[(size_t)(row + r) * 512 + col] = v;
                else if constexpr (OBF16)
                    O[(size_t)(row + r) * 512 + col] = f2b(v);
                else
                    O[(size_t)(row + r) * 512 + col] = f2h(v);
            }
        }
    }
}

// ---- Fast-path kernels (fp16 A via gload_lds) ------------------------------
// Fused Q/K/V projection: 128x128 tiles, XCD-swizzled 1D grid of 768 blocks.
__global__ __launch_bounds__(256, 3) void gemm_qkv_gl(
    const ushort_t* __restrict__ srch, const ushort_t* __restrict__ tgth,
    const ushort_t* __restrict__ WtQ, const ushort_t* __restrict__ WtK,
    const ushort_t* __restrict__ WtV,
    const float* __restrict__ bq, const float* __restrict__ bk,
    const float* __restrict__ bv,
    ushort_t* __restrict__ Qb, ushort_t* __restrict__ Kb,
    ushort_t* __restrict__ Vb) {
    const int id = blockIdx.x;
    const int xcd = id & 7;
    const int g = id >> 3;        // 0..95
    const int mgrp = g / 12;      // 0..7
    const int r = g % 12;
    const int z = r >> 2;         // 0..2
    const int bn = (r & 3) * 128;
    const int bm = (xcd + 8 * mgrp) * 128;

    const ushort_t* A = (z == 0) ? srch : tgth;
    const ushort_t* Wt = (z == 0) ? WtQ : (z == 1) ? WtK : WtV;
    const float* bias = (z == 0) ? bq : (z == 1) ? bk : bv;
    ushort_t* O = (z == 0) ? Qb : (z == 1) ? Kb : Vb;
    gemm_body_gl<ushort_t, 128, false>(A, Wt, bias, O, bm, bn);
}

// Output projection: 128x128 tiles, 256 blocks = 1/CU, XCD-swizzled.
template <typename OT, bool OBF16>
__global__ __launch_bounds__(256, 3) void gemm_o_gl(
    const ushort_t* __restrict__ A, const ushort_t* __restrict__ Wt,
    const float* __restrict__ bias, OT* __restrict__ O) {
    const int id = blockIdx.x;
    const int xcd = id & 7;
    const int g = id >> 3;        // 0..31
    const int mgrp = g >> 2;      // 0..7
    const int bn = (g & 3) * 128;
    const int bm = (xcd + 8 * mgrp) * 128;
    gemm_body_gl<OT, 128, OBF16>(A, Wt, bias, O, bm, bn);
}

// ---- Fallback kernels (reg-staging body) -----------------------------------
template <typename AT, typename BT>
__global__ __launch_bounds__(256, 3) void gemm_qkv(
    const AT* __restrict__ src, const AT* __restrict__ tgt,
    const BT* __restrict__ WtQ, const BT* __restrict__ WtK,
    const BT* __restrict__ WtV,
    const float* __restrict__ bq, const float* __restrict__ bk,
    const float* __restrict__ bv,
    ushort_t* __restrict__ Qb, ushort_t* __restrict__ Kb,
    ushort_t* __restrict__ Vb) {
    const int id = blockIdx.x;
    const int xcd = id & 7;
    const int g = id >> 3;        // 0..95
    const int mgrp = g / 12;      // 0..7
    const int r = g % 12;
    const int z = r >> 2;         // 0..2
    const int bn = (r & 3) * 128;
    const int bm = (xcd + 8 * mgrp) * 128;

    const AT* A = (z == 0) ? src : tgt;
    const BT* Wt = (z == 0) ? WtQ : (z == 1) ? WtK : WtV;
    const float* bias = (z == 0) ? bq : (z == 1) ? bk : bv;
    ushort_t* O = (z == 0) ? Qb : (z == 1) ? Kb : Vb;
    gemm_body<AT, BT, ushort_t, 128, false>(A, Wt, bias, O, bm, bn);
}

template <typename BT, typename OT, bool OBF16>
__global__ __launch_bounds__(256, 3) void gemm_o(const ushort_t* __restrict__ A,
                                                 const BT* __restrict__ Wt,
                                                 const float* __restrict__ bias,
                                                 OT* __restrict__ O) {
    const int id = blockIdx.x;
    const int xcd = id & 7;
    const int g = id >> 3;        // 0..31
    const int mgrp = g >> 2;      // 0..7
    const int bn = (g & 3) * 128;
    const int bm = (xcd + 8 * mgrp) * 128;
    gemm_body<ushort_t, BT, OT, 128, OBF16>(A, Wt, bias, O, bm, bn);
}

// ---------------------------------------------------------------------------
// Gather attention — R3-exact (proven 44.2us, VGPR 32, occ 70%, no spill):
// fp16 intermediates + v_dot2_f32_f16, 16-row sub-phases, register prefetch
// pipeline, 8 barriers. O aliases Q (same-row only). XCD batch swizzle.
// ---------------------------------------------------------------------------
#define KVSTRIDE 520
template <typename IT>
__global__ __launch_bounds__(256, 7) void attn_kernel(const ushort_t* Q,
                                                      const ushort_t* __restrict__ K,
                                                      const ushort_t* __restrict__ V,
                                                      const IT* __restrict__ idx,
                                                      const float* __restrict__ wts,
                                                      ushort_t* O) {
    __shared__ uint32_t qs[16][20];         // raw fp16 pairs; row=h*2+half
    __shared__ ushort_t kvs[16][KVSTRIDE];  // 16-row staging buffer
    __shared__ float ps[H_][KNN_];
    __shared__ int idxs[KNN_];
    __shared__ float ws[KNN_];

    const int t = threadIdx.x;
    const int id = blockIdx.x;
    const int xcd = id & 7;
    const int slot = id >> 3;
    const int b = xcd >> 2;
    const int bq = b * HW_ + (xcd & 3) * 1024 + slot;
    const size_t qoff = (size_t)bq * C_;

    // Q is fp16: raw pair copy, no conversion
    qs[t >> 4][t & 15] = *(const uint32_t*)(Q + qoff + 2 * t);
    if (t < KNN_) {
        idxs[t] = (int)idx[(size_t)bq * KNN_ + t];
        ws[t] = wts[(size_t)bq * KNN_ + t];
    }
    __syncthreads();  // (1) idxs/ws/qs ready

    const ushort_t* Kbase = K + (size_t)b * NTGT_ * C_;
    const ushort_t* Vbase = V + (size_t)b * NTGT_ * C_;
    const int prow = t >> 4;          // staging row 0..15 (16 lanes/row)
    const int pcol = (t & 15) * 8;    // element offset; +j*128 covers 512

    const int h = t >> 5;
    const int l5 = t & 31;
    const int nl = l5 & 15;
    const int half = l5 >> 4;
    const int koff = h * 64 + half * 32;

    uint4 r0, r1, r2, r3;
    // K rows 0-15 -> regs -> LDS
    {
        const ushort_t* p = Kbase + (size_t)idxs[prow] * C_ + pcol;
        r0 = *(const uint4*)(p);       r1 = *(const uint4*)(p + 128);
        r2 = *(const uint4*)(p + 256); r3 = *(const uint4*)(p + 384);
    }
    // hoist Q fragment into regs (LDS; independent counter from globals)
    const int qrow = h * 2 + half;
    uint4 q0 = *(const uint4*)&qs[qrow][0];
    uint4 q1 = *(const uint4*)&qs[qrow][4];
    uint4 q2 = *(const uint4*)&qs[qrow][8];
    uint4 q3 = *(const uint4*)&qs[qrow][12];

    *(uint4*)&kvs[prow][pcol + 0]   = r0;
    *(uint4*)&kvs[prow][pcol + 128] = r1;
    *(uint4*)&kvs[prow][pcol + 256] = r2;
    *(uint4*)&kvs[prow][pcol + 384] = r3;
    // issue K rows 16-31 early (latency hides under dot phase A)
    {
        const ushort_t* p = Kbase + (size_t)idxs[prow + 16] * C_ + pcol;
        r0 = *(const uint4*)(p);       r1 = *(const uint4*)(p + 128);
        r2 = *(const uint4*)(p + 256); r3 = *(const uint4*)(p + 384);
    }
    __syncthreads();  // (2) K rows 0-15 staged

    float l0, l1;
    {
        uint4 kv0 = *(const uint4*)&kvs[nl][koff + 0];
        uint4 kv1 = *(const uint4*)&kvs[nl][koff + 8];
        uint4 kv2 = *(const uint4*)&kvs[nl][koff + 16];
        uint4 kv3 = *(const uint4*)&kvs[nl][koff + 24];
        float da = 0.f, db = 0.f;
        da = dot2acc(kv0.x, q0.x, da); da = dot2acc(kv0.y, q0.y, da);
        da = dot2acc(kv0.z, q0.z, da); da = dot2acc(kv0.w, q0.w, da);
        db = dot2acc(kv1.x, q1.x, db); db = dot2acc(kv1.y, q1.y, db);
        db = dot2acc(kv1.z, q1.z, db); db = dot2acc(kv1.w, q1.w, db);
        da = dot2acc(kv2.x, q2.x, da); da = dot2acc(kv2.y, q2.y, da);
        da = dot2acc(kv2.z, q2.z, da); da = dot2acc(kv2.w, q2.w, da);
        db = dot2acc(kv3.x, q3.x, db); db = dot2acc(kv3.y, q3.y, db);
        db = dot2acc(kv3.z, q3.z, db); db = dot2acc(kv3.w, q3.w, db);
        float dot = da + db;
        dot += __shfl_xor(dot, 16);   // combine halves: full 64-elem dot
        l0 = dot * 0.125f + ws[nl];
    }
    __syncthreads();  // (3) K-A reads complete
    // publish K rows 16-31; issue V rows 0-15
    *(uint4*)&kvs[prow][pcol + 0]   = r0;
    *(uint4*)&kvs[prow][pcol + 128] = r1;
    *(uint4*)&kvs[prow][pcol + 256] = r2;
    *(uint4*)&kvs[prow][pcol + 384] = r3;
    {
        const ushort_t* p = Vbase + (size_t)idxs[prow] * C_ + pcol;
        r0 = *(const uint4*)(p);       r1 = *(const uint4*)(p + 128);
        r2 = *(const uint4*)(p + 256); r3 = *(const uint4*)(p + 384);
    }
    __syncthreads();  // (4) K rows 16-31 staged
    {
        uint4 kv0 = *(const uint4*)&kvs[nl][koff + 0];
        uint4 kv1 = *(const uint4*)&kvs[nl][koff + 8];
        uint4 kv2 = *(const uint4*)&kvs[nl][koff + 16];
        uint4 kv3 = *(const uint4*)&kvs[nl][koff + 24];
        float da = 0.f, db = 0.f;
        da = dot2acc(kv0.x, q0.x, da); da = dot2acc(kv0.y, q0.y, da);
        da = dot2acc(kv0.z, q0.z, da); da = dot2acc(kv0.w, q0.w, da);
        db = dot2acc(kv1.x, q1.x, db); db = dot2acc(kv1.y, q1.y, db);
        db = dot2acc(kv1.z, q1.z, db); db = dot2acc(kv1.w, q1.w, db);
        da = dot2acc(kv2.x, q2.x, da); da = dot2acc(kv2.y, q2.y, da);
        da = dot2acc(kv2.z, q2.z, da); da = dot2acc(kv2.w, q2.w, da);
        db = dot2acc(kv3.x, q3.x, db); db = dot2acc(kv3.y, q3.y, db);
        db = dot2acc(kv3.z, q3.z, db); db = dot2acc(kv3.w, q3.w, db);
        float dot = da + db;
        dot += __shfl_xor(dot, 16);
        l1 = dot * 0.125f + ws[nl + 16];
    }
    // softmax over 32 logits; each n present in exactly 2 lanes of the group
    {
        float m = fmaxf(l0, l1);
#pragma unroll
        for (int o = 16; o > 0; o >>= 1) m = fmaxf(m, __shfl_xor(m, o));
        float e0 = __expf(l0 - m), e1 = __expf(l1 - m);
        float s = e0 + e1;
#pragma unroll
        for (int o = 16; o > 0; o >>= 1) s += __shfl_xor(s, o);
        const float inv = 2.0f / s;   // duplicates double-count: exact /2
        ps[h][nl] = e0 * inv;         // duplicate lanes write same value
        ps[h][nl + 16] = e1 * inv;
    }
    __syncthreads();  // (5) K-B reads + ps writes complete
    // publish V rows 0-15; issue V rows 16-31
    *(uint4*)&kvs[prow][pcol + 0]   = r0;
    *(uint4*)&kvs[prow][pcol + 128] = r1;
    *(uint4*)&kvs[prow][pcol + 256] = r2;
    *(uint4*)&kvs[prow][pcol + 384] = r3;
    {
        const ushort_t* p = Vbase + (size_t)idxs[prow + 16] * C_ + pcol;
        r0 = *(const uint4*)(p);       r1 = *(const uint4*)(p + 128);
        r2 = *(const uint4*)(p + 256); r3 = *(const uint4*)(p + 384);
    }
    __syncthreads();  // (6) V rows 0-15 staged

    const int d2 = l5 * 2;
    float a0 = 0.f, a1 = 0.f;
#pragma unroll
    for (int nn = 0; nn < 16; ++nn) {
        uint32_t vv = *(const uint32_t*)&kvs[nn][h * DH_ + d2];
        float p = ps[h][nn];
        a0 = fmaf(p, h2f((ushort_t)(vv & 0xffffu)), a0);
        a1 = fmaf(p, h2f((ushort_t)(vv >> 16)), a1);
    }
    __syncthreads();  // (7) V-A reads complete
    *(uint4*)&kvs[prow][pcol + 0]   = r0;
    *(uint4*)&kvs[prow][pcol + 128] = r1;
    *(uint4*)&kvs[prow][pcol + 256] = r2;
    *(uint4*)&kvs[prow][pcol + 384] = r3;
    __syncthreads();  // (8) V rows 16-31 staged
#pragma unroll
    for (int nn = 0; nn < 16; ++nn) {
        uint32_t vv = *(const uint32_t*)&kvs[nn][h * DH_ + d2];
        float p = ps[h][nn + 16];
        a0 = fmaf(p, h2f((ushort_t)(vv & 0xffffu)), a0);
        a1 = fmaf(p, h2f((ushort_t)(vv >> 16)), a1);
    }
    *(uint32_t*)(O + qoff + h * DH_ + d2) = pkh(a0, a1);
}

// ---------------------------------------------------------------------------
static int elem_bytes(const void* p, size_t n, int dflt) {
    size_t sz = 0;
    hipError_t err = hipPointerGetAttribute(
        &sz, HIP_POINTER_ATTRIBUTE_RANGE_SIZE, (hipDeviceptr_t)(uintptr_t)p);
    if (err == hipSuccess && sz >= n && (sz % n) == 0) {
        size_t b = sz / n;
        if (b == 2 || b == 4 || b == 8) return (int)b;
    }
    return dflt;
}

extern "C" void kernel_launch(void* const* d_in, const int* in_sizes, int n_in,
                              void* d_out, int out_size, void* d_ws, size_t ws_size,
                              hipStream_t stream) {
    const float* src  = (const float*)d_in[0];
    const float* tgt  = (const float*)d_in[1];
    const void*  idxp = d_in[2];
    const float* wtp  = (const float*)d_in[3];
    float* Wq = (float*)d_in[4];  const float* bq = (const float*)d_in[5];
    float* Wk = (float*)d_in[6];  const float* bk = (const float*)d_in[7];
    float* Wv = (float*)d_in[8];  const float* bv = (const float*)d_in[9];
    float* Wo = (float*)d_in[10]; const float* bo = (const float*)d_in[11];

    const size_t NELEM = (size_t)M_ * C_;          // 4,194,304
    const size_t WELEM = (size_t)C_ * C_;          // 262,144
    const size_t NIDX  = (size_t)B_ * HW_ * KNN_;

    const int ib = elem_bytes(idxp, NIDX, 4);
    const int ob = elem_bytes(d_out, NELEM, 4);

    dim3 blk(256);

    // ws: Q fp16 [0,8MB) | K fp16 [8,16MB) | fp16 Wt x4 [16,18MB)
    //     | optional src16 [18,26.4MB) | tgt16 [26.4,34.8MB).
    // V fp16 in d_out (consumed by attn before gemm_o overwrites);
    // attn output aliases Q.
    ushort_t* Qb = (ushort_t*)d_ws;
    ushort_t* Kb = Qb + NELEM;
    ushort_t* Vb = (ushort_t*)d_out;
    ushort_t* Ob = Qb;

    const bool wfit  = ws_size >= (2 * NELEM + 4 * WELEM) * sizeof(ushort_t);
    const bool wfit2 = ws_size >= (4 * NELEM + 4 * WELEM) * sizeof(ushort_t);

    if (wfit) {
        // fp16 transposed weights in ws tail (no input mutation)
        ushort_t* T = Kb + NELEM;
        ushort_t* WtQ = T;
        ushort_t* WtK = T + WELEM;
        ushort_t* WtV = T + 2 * WELEM;
        ushort_t* WtO = T + 3 * WELEM;

        transpose_cvt4<<<dim3(16, 16, 4), blk, 0, stream>>>(
            Wq, Wk, Wv, Wo, WtQ, WtK, WtV, WtO);

        if (wfit2) {
            // pre-convert src/tgt -> fp16: enables full gload_lds staging
            ushort_t* srch = T + 4 * WELEM;
            ushort_t* tgth = srch + NELEM;
            cvt_f32_f16_2<<<dim3(4096, 2), blk, 0, stream>>>(
                src, tgt, srch, tgth);
            gemm_qkv_gl<<<dim3(768), blk, 0, stream>>>(
                srch, tgth, WtQ, WtK, WtV, bq, bk, bv, Qb, Kb, Vb);
        } else {
            gemm_qkv<float, ushort_t><<<dim3(768), blk, 0, stream>>>(
                src, tgt, WtQ, WtK, WtV, bq, bk, bv, Qb, Kb, Vb);
        }

        if (ib == 8)
            attn_kernel<long long><<<dim3(B_ * HW_), blk, 0, stream>>>(
                Qb, Kb, Vb, (const long long*)idxp, wtp, Ob);
        else
            attn_kernel<int><<<dim3(B_ * HW_), blk, 0, stream>>>(
                Qb, Kb, Vb, (const int*)idxp, wtp, Ob);

        if (ob == 2)
            gemm_o_gl<ushort_t, true><<<dim3(256), blk, 0, stream>>>(
                Ob, WtO, bo, (ushort_t*)d_out);
        else
            gemm_o_gl<float, false><<<dim3(256), blk, 0, stream>>>(
                Ob, WtO, bo, (float*)d_out);
    } else {
        // fallback: in-place fp32 transpose, fp32-B GEMMs (reg-staging body)
        transpose_inplace4_f32<<<dim3(136, 4), blk, 0, stream>>>(Wq, Wk, Wv, Wo);

        gemm_qkv<float, float><<<dim3(768), blk, 0, stream>>>(
            src, tgt, Wq, Wk, Wv, bq, bk, bv, Qb, Kb, Vb);

        if (ib == 8)
            attn_kernel<long long><<<dim3(B_ * HW_), blk, 0, stream>>>(
                Qb, Kb, Vb, (const long long*)idxp, wtp, Ob);
        else
            attn_kernel<int><<<dim3(B_ * HW_), blk, 0, stream>>>(
                Qb, Kb, Vb, (const int*)idxp, wtp, Ob);

        if (ob == 2)
            gemm_o<float, ushort_t, true><<<dim3(256), blk, 0, stream>>>(
                Ob, Wo, bo, (ushort_t*)d_out);
        else
            gemm_o<float, float, false><<<dim3(256), blk, 0, stream>>>(
                Ob, Wo, bo, (float*)d_out);
    }
}

// Round 12
// 179.429 us; speedup vs baseline: 1.0199x; 1.0199x over previous
//
#include <hip/hip_runtime.h>
#include <hip/hip_bf16.h>
#include <stdint.h>
#include <type_traits>

// Problem constants
#define B_    2
#define HW_   4096
#define NTGT_ 4096
#define C_    512
#define H_    8
#define KNN_  32
#define DH_   64
#define M_    (B_ * HW_)

typedef unsigned short ushort_t;
typedef _Float16 f16x8 __attribute__((ext_vector_type(8)));
typedef __fp16 hf2 __attribute__((ext_vector_type(2)));
typedef float floatx4 __attribute__((ext_vector_type(4)));

// ---- fp16 helpers (intermediates are IEEE fp16: more mantissa than bf16)
__device__ __forceinline__ uint32_t pkh(float x, float y) {
    union { hf2 h; uint32_t u; } c;
    c.h = __builtin_amdgcn_cvt_pkrtz(x, y);   // v_cvt_pkrtz_f16_f32
    return c.u;
}
__device__ __forceinline__ ushort_t f2h(float f) {
    return (ushort_t)(pkh(f, 0.f) & 0xffffu);
}
__device__ __forceinline__ float h2f(ushort_t u) {
    union { ushort_t s; __fp16 h; } x;
    x.s = u;
    return (float)x.h;                         // v_cvt_f32_f16
}
// bf16 round-to-nearest (final-output defensive path only)
__device__ __forceinline__ ushort_t f2b(float f) {
    union { float f; uint32_t i; } x;
    x.f = f;
    uint32_t r = x.i + 0x7fffu + ((x.i >> 16) & 1u);
    return (ushort_t)(r >> 16);
}
// 2-way fp16 dot with f32 accumulate: v_dot2_f32_f16
__device__ __forceinline__ float dot2acc(uint32_t a, uint32_t b, float c) {
#if __has_builtin(__builtin_amdgcn_fdot2)
    union { uint32_t u; hf2 h; } xa, xb;
    xa.u = a; xb.u = b;
    return __builtin_amdgcn_fdot2(xa.h, xb.h, c, false);
#else
    c = fmaf(h2f((ushort_t)(a & 0xffffu)), h2f((ushort_t)(b & 0xffffu)), c);
    return fmaf(h2f((ushort_t)(a >> 16)), h2f((ushort_t)(b >> 16)), c);
#endif
}
__device__ __forceinline__ uint4 pack8(const float4& a, const float4& b) {
    return make_uint4(pkh(a.x, a.y), pkh(a.z, a.w), pkh(b.x, b.y), pkh(b.z, b.w));
}
// Async global->LDS, 16B per lane. LDS dest = wave-uniform base + lane*16B;
// global source is per-lane. vmcnt-counted; __syncthreads() drains it.
__device__ __forceinline__ void gl16(const ushort_t* g, ushort_t* l) {
    __builtin_amdgcn_global_load_lds(
        (__attribute__((address_space(1))) void*)(g),
        (__attribute__((address_space(3))) void*)(l), 16, 0, 0);
}

// ---------------------------------------------------------------------------
// Out-of-place transpose+convert: T_fp16[n][k] = W_fp32[k][n], 4 matrices.
// No input mutation. grid (16,16,4).
// ---------------------------------------------------------------------------
__global__ __launch_bounds__(256) void transpose_cvt4(
    const float* __restrict__ W0, const float* __restrict__ W1,
    const float* __restrict__ W2, const float* __restrict__ W3,
    ushort_t* __restrict__ T0, ushort_t* __restrict__ T1,
    ushort_t* __restrict__ T2, ushort_t* __restrict__ T3) {
    __shared__ float tile[32][33];

    const float* W = (blockIdx.z == 0) ? W0 : (blockIdx.z == 1) ? W1
                     : (blockIdx.z == 2) ? W2 : W3;
    ushort_t* T = (blockIdx.z == 0) ? T0 : (blockIdx.z == 1) ? T1
                  : (blockIdx.z == 2) ? T2 : T3;

    const int k0 = blockIdx.x * 32;
    const int n0 = blockIdx.y * 32;
    const int t = threadIdx.x;
    const int r = t >> 3;
    const int c0 = (t & 7) * 4;

    float4 d = *(const float4*)&W[(size_t)(k0 + r) * 512 + n0 + c0];
    tile[r][c0 + 0] = d.x; tile[r][c0 + 1] = d.y;
    tile[r][c0 + 2] = d.z; tile[r][c0 + 3] = d.w;
    __syncthreads();

    uint2 o;
    o.x = pkh(tile[c0 + 0][r], tile[c0 + 1][r]);
    o.y = pkh(tile[c0 + 2][r], tile[c0 + 3][r]);
    *(uint2*)&T[(size_t)(n0 + r) * 512 + k0 + c0] = o;
}

// ---------------------------------------------------------------------------
// IN-PLACE fp32 transpose fallback (if ws can't hold fp16 weights).
// ---------------------------------------------------------------------------
__global__ __launch_bounds__(256) void transpose_inplace4_f32(
    float* W0, float* W1, float* W2, float* W3) {
    __shared__ float ta[32][33];
    __shared__ float tb[32][33];

    float* W = (blockIdx.y == 0) ? W0 : (blockIdx.y == 1) ? W1
               : (blockIdx.y == 2) ? W2 : W3;

    int p = blockIdx.x;
    int i = 0, acc = 0;
    while (acc + (16 - i) <= p) { acc += 16 - i; ++i; }
    const int j = i + (p - acc);

    const int t = threadIdx.x;
    const int r = t >> 3;
    const int c0 = (t & 7) * 4;

    {
        float4 d = *(const float4*)&W[(size_t)(i * 32 + r) * 512 + j * 32 + c0];
        ta[r][c0 + 0] = d.x; ta[r][c0 + 1] = d.y;
        ta[r][c0 + 2] = d.z; ta[r][c0 + 3] = d.w;
    }
    if (i != j) {
        float4 d = *(const float4*)&W[(size_t)(j * 32 + r) * 512 + i * 32 + c0];
        tb[r][c0 + 0] = d.x; tb[r][c0 + 1] = d.y;
        tb[r][c0 + 2] = d.z; tb[r][c0 + 3] = d.w;
    }
    __syncthreads();

    *(float4*)&W[(size_t)(j * 32 + r) * 512 + i * 32 + c0] =
        make_float4(ta[c0 + 0][r], ta[c0 + 1][r], ta[c0 + 2][r], ta[c0 + 3][r]);
    if (i != j)
        *(float4*)&W[(size_t)(i * 32 + r) * 512 + j * 32 + c0] =
            make_float4(tb[c0 + 0][r], tb[c0 + 1][r], tb[c0 + 2][r], tb[c0 + 3][r]);
}

// ---------------------------------------------------------------------------
// gload_lds GEMM body (fp16 A/B only): linear LDS tiles staged entirely by
// global_load_lds width=16. Used for gemm_o (A = attn out, already fp16).
// Per wave per K-step: 3-4 gload_lds + ds_reads + MFMAs, 2 barriers.
// ---------------------------------------------------------------------------
template <typename OT, int BN, bool OBF16>
__device__ __forceinline__ void gemm_body_gl(const ushort_t* __restrict__ A,
                                             const ushort_t* __restrict__ Wt,
                                             const float* __restrict__ bias,
                                             OT* __restrict__ O,
                                             int bm, int bn) {
    constexpr int NJ = BN / 32;
    __shared__ ushort_t Asf[128 * 32];   // [m][k] fp16, linear
    __shared__ ushort_t Bsf[BN * 32];    // [n][k] fp16, linear

    const int t = threadIdx.x;
    const int lane = t & 63;
    const int wv = t >> 6;
    const int wr = (wv >> 1) * 64;
    const int wc = (wv & 1) * (BN / 2);
    const int r16 = lane & 15;
    const int quad = lane >> 4;

    // gload_lds lane map: wave wv chunk covers 16 rows; lane l -> row
    // wv*16 + (l>>2), col (l&3)*8 (16B). LDS dest base wave-uniform.
    const int srow = wv * 16 + (lane >> 2);
    const int scol = (lane & 3) * 8;
    const ushort_t* ag0 = &A[(size_t)(bm + srow) * 512 + scol];
    const ushort_t* ag1 = &A[(size_t)(bm + 64 + srow) * 512 + scol];
    const ushort_t* bg0 = &Wt[(size_t)(bn + (srow & (BN - 1))) * 512 + scol];
    ushort_t* al0 = &Asf[wv * 512];
    ushort_t* al1 = &Asf[2048 + wv * 512];
    ushort_t* bl0 = &Bsf[(wv * 512) & (BN * 32 - 1)];

    floatx4 acc[4][NJ] = {};

    for (int kt = 0; kt < 512; kt += 32) {
        gl16(ag0 + kt, al0);
        gl16(ag1 + kt, al1);
        gl16(bg0 + kt, bl0);   // BN=64: waves 0-3 cover rows 0-63 (wv*16)
        __syncthreads();  // vmcnt(0) drain: tile staged & visible

        f16x8 af[4], bf[NJ];
#pragma unroll
        for (int i = 0; i < 4; ++i)
            af[i] = *(const f16x8*)&Asf[(wr + i * 16 + r16) * 32 + quad * 8];
#pragma unroll
        for (int j = 0; j < NJ; ++j)
            bf[j] = *(const f16x8*)&Bsf[(wc + j * 16 + r16) * 32 + quad * 8];
#pragma unroll
        for (int i = 0; i < 4; ++i)
#pragma unroll
            for (int j = 0; j < NJ; ++j)
                acc[i][j] = __builtin_amdgcn_mfma_f32_16x16x32_f16(
                    af[i], bf[j], acc[i][j], 0, 0, 0);
        __syncthreads();  // frag reads done before next stage overwrites
    }

    // D layout: col=lane&15, row=quad*4+reg [m89]
#pragma unroll
    for (int j = 0; j < NJ; ++j) {
        const int col = bn + wc + j * 16 + r16;
        const float bj = bias[col];
#pragma unroll
        for (int i = 0; i < 4; ++i) {
            const int row = bm + wr + i * 16 + quad * 4;
#pragma unroll
            for (int r = 0; r < 4; ++r) {
                float v = acc[i][j][r] + bj;
                if constexpr (std::is_same<OT, float>::value)
                    O[(size_t)(row + r) * 512 + col] = v;
                else if constexpr (OBF16)
                    O[(size_t)(row + r) * 512 + col] = f2b(v);
                else
                    O[(size_t)(row + r) * 512 + col] = f2h(v);
            }
        }
    }
}

// ---------------------------------------------------------------------------
// Reg-staging GEMM body (R4-proven): handles fp32 A (pack8 cvt in staging).
// ---------------------------------------------------------------------------
template <typename AT, typename BT, typename OT, int BN, bool OBF16>
__device__ __forceinline__ void gemm_body(const AT* __restrict__ A,
                                          const BT* __restrict__ Wt,
                                          const float* __restrict__ bias,
                                          OT* __restrict__ O,
                                          int bm, int bn) {
    constexpr int NJ = BN / 32;          // MFMAs in n per wave
    __shared__ ushort_t As[128][40];     // [m][k] fp16, 80B stride
    __shared__ ushort_t Bs[BN][40];      // [n][k] fp16

    const int t = threadIdx.x;
    const int lr = t >> 2;        // 0..63
    const int lc = (t & 3) * 8;   // 0,8,16,24

    const int lane = t & 63;
    const int wv = t >> 6;
    const int wr = (wv >> 1) * 64;
    const int wc = (wv & 1) * (BN / 2);
    const int r16 = lane & 15;
    const int quad = lane >> 4;

    floatx4 acc[4][NJ] = {};

    float4 fa0, fa1, fa2, fa3, fb0, fb1, fb2, fb3;
    uint4 ua0, ua1, ub0, ub1;

    // prefetch kt = 0
    if constexpr (std::is_same<AT, float>::value) {
        const float* p0 = &A[(size_t)(bm + lr) * 512 + lc];
        const float* p1 = &A[(size_t)(bm + lr + 64) * 512 + lc];
        fa0 = *(const float4*)p0; fa1 = *(const float4*)(p0 + 4);
        fa2 = *(const float4*)p1; fa3 = *(const float4*)(p1 + 4);
    } else {
        ua0 = *(const uint4*)&A[(size_t)(bm + lr) * 512 + lc];
        ua1 = *(const uint4*)&A[(size_t)(bm + lr + 64) * 512 + lc];
    }
    if constexpr (std::is_same<BT, float>::value) {
        const float* p0 = &Wt[(size_t)(bn + lr) * 512 + lc];
        fb0 = *(const float4*)p0; fb1 = *(const float4*)(p0 + 4);
        if constexpr (BN == 128) {
            const float* p1 = &Wt[(size_t)(bn + lr + 64) * 512 + lc];
            fb2 = *(const float4*)p1; fb3 = *(const float4*)(p1 + 4);
        }
    } else {
        ub0 = *(const uint4*)&Wt[(size_t)(bn + lr) * 512 + lc];
        if constexpr (BN == 128)
            ub1 = *(const uint4*)&Wt[(size_t)(bn + lr + 64) * 512 + lc];
    }

    for (int kt = 0; kt < 512; kt += 32) {
        __syncthreads();  // prior iteration's fragment reads complete
        if constexpr (std::is_same<AT, float>::value) {
            *(uint4*)&As[lr][lc] = pack8(fa0, fa1);
            *(uint4*)&As[lr + 64][lc] = pack8(fa2, fa3);
        } else {
            *(uint4*)&As[lr][lc] = ua0;
            *(uint4*)&As[lr + 64][lc] = ua1;
        }
        if constexpr (std::is_same<BT, float>::value) {
            *(uint4*)&Bs[lr][lc] = pack8(fb0, fb1);
            if constexpr (BN == 128) *(uint4*)&Bs[lr + 64][lc] = pack8(fb2, fb3);
        } else {
            *(uint4*)&Bs[lr][lc] = ub0;
            if constexpr (BN == 128) *(uint4*)&Bs[lr + 64][lc] = ub1;
        }
        __syncthreads();

        if (kt + 32 < 512) {  // issue next-tile loads; wait lands at publish
            const int k2 = kt + 32;
            if constexpr (std::is_same<AT, float>::value) {
                const float* p0 = &A[(size_t)(bm + lr) * 512 + k2 + lc];
                const float* p1 = &A[(size_t)(bm + lr + 64) * 512 + k2 + lc];
                fa0 = *(const float4*)p0; fa1 = *(const float4*)(p0 + 4);
                fa2 = *(const float4*)p1; fa3 = *(const float4*)(p1 + 4);
            } else {
                ua0 = *(const uint4*)&A[(size_t)(bm + lr) * 512 + k2 + lc];
                ua1 = *(const uint4*)&A[(size_t)(bm + lr + 64) * 512 + k2 + lc];
            }
            if constexpr (std::is_same<BT, float>::value) {
                const float* p0 = &Wt[(size_t)(bn + lr) * 512 + k2 + lc];
                fb0 = *(const float4*)p0; fb1 = *(const float4*)(p0 + 4);
                if constexpr (BN == 128) {
                    const float* p1 = &Wt[(size_t)(bn + lr + 64) * 512 + k2 + lc];
                    fb2 = *(const float4*)p1; fb3 = *(const float4*)(p1 + 4);
                }
            } else {
                ub0 = *(const uint4*)&Wt[(size_t)(bn + lr) * 512 + k2 + lc];
                if constexpr (BN == 128)
                    ub1 = *(const uint4*)&Wt[(size_t)(bn + lr + 64) * 512 + k2 + lc];
            }
        }

        f16x8 af[4], bf[NJ];
#pragma unroll
        for (int i = 0; i < 4; ++i)
            af[i] = *(const f16x8*)&As[wr + i * 16 + r16][quad * 8];
#pragma unroll
        for (int j = 0; j < NJ; ++j)
            bf[j] = *(const f16x8*)&Bs[wc + j * 16 + r16][quad * 8];
#pragma unroll
        for (int i = 0; i < 4; ++i)
#pragma unroll
            for (int j = 0; j < NJ; ++j)
                acc[i][j] = __builtin_amdgcn_mfma_f32_16x16x32_f16(
                    af[i], bf[j], acc[i][j], 0, 0, 0);
    }

    // D layout: col=lane&15, row=quad*4+reg [m89]
#pragma unroll
    for (int j = 0; j < NJ; ++j) {
        const int col = bn + wc + j * 16 + r16;
        const float bj = bias[col];
#pragma unroll
        for (int i = 0; i < 4; ++i) {
            const int row = bm + wr + i * 16 + quad * 4;
#pragma unroll
            for (int r = 0; r < 4; ++r) {
                float v = acc[i][j][r] + bj;
                if constexpr (std::is_same<OT, float>::value)
                    O[(size_t)(row + r) * 512 + col] = v;
                else if constexpr (OBF16)
                    O[(size_t)(row + r) * 512 + col] = f2b(v);
                else
                    O[(size_t)(row + r) * 512 + col] = f2h(v);
            }
        }
    }
}

// Fused Q/K/V projection: 128x128 tiles, XCD-swizzled 1D grid of 768 blocks.
// fp32 A (no cvt pre-pass — R11 showed gl-qkv ~= cvt cost, net wash).
template <typename AT, typename BT>
__global__ __launch_bounds__(256, 3) void gemm_qkv(
    const AT* __restrict__ src, const AT* __restrict__ tgt,
    const BT* __restrict__ WtQ, const BT* __restrict__ WtK,
    const BT* __restrict__ WtV,
    const float* __restrict__ bq, const float* __restrict__ bk,
    const float* __restrict__ bv,
    ushort_t* __restrict__ Qb, ushort_t* __restrict__ Kb,
    ushort_t* __restrict__ Vb) {
    const int id = blockIdx.x;
    const int xcd = id & 7;
    const int g = id >> 3;        // 0..95
    const int mgrp = g / 12;      // 0..7
    const int r = g % 12;
    const int z = r >> 2;         // 0..2
    const int bn = (r & 3) * 128;
    const int bm = (xcd + 8 * mgrp) * 128;

    const AT* A = (z == 0) ? src : tgt;
    const BT* Wt = (z == 0) ? WtQ : (z == 1) ? WtK : WtV;
    const float* bias = (z == 0) ? bq : (z == 1) ? bk : bv;
    ushort_t* O = (z == 0) ? Qb : (z == 1) ? Kb : Vb;
    gemm_body<AT, BT, ushort_t, 128, false>(A, Wt, bias, O, bm, bn);
}

// Output projection: BN=64, 512 blocks (2 tiles/CU — R10/R11's 256-block
// BN=128 gave 1 block/CU, defeating cross-block wave overlap [m114]).
// gl-staging: A (attn out) is already fp16.
template <typename OT, bool OBF16>
__global__ __launch_bounds__(256, 4) void gemm_o_gl(
    const ushort_t* __restrict__ A, const ushort_t* __restrict__ Wt,
    const float* __restrict__ bias, OT* __restrict__ O) {
    const int id = blockIdx.x;
    const int xcd = id & 7;
    const int g = id >> 3;        // 0..63
    const int mgrp = g >> 3;      // 0..7
    const int bn = (g & 7) * 64;
    const int bm = (xcd + 8 * mgrp) * 128;
    gemm_body_gl<OT, 64, OBF16>(A, Wt, bias, O, bm, bn);
}

// Fallback gemm_o (fp32 weights, reg-staging)
template <typename BT, typename OT, bool OBF16>
__global__ __launch_bounds__(256, 4) void gemm_o(const ushort_t* __restrict__ A,
                                                 const BT* __restrict__ Wt,
                                                 const float* __restrict__ bias,
                                                 OT* __restrict__ O) {
    const int id = blockIdx.x;
    const int xcd = id & 7;
    const int g = id >> 3;        // 0..63
    const int mgrp = g >> 3;      // 0..7
    const int bn = (g & 7) * 64;
    const int bm = (xcd + 8 * mgrp) * 128;
    gemm_body<ushort_t, BT, OT, 64, OBF16>(A, Wt, bias, O, bm, bn);
}

// ---------------------------------------------------------------------------
// Gather attention — R3-exact (proven 44.2us, VGPR 32, occ 70%, no spill):
// fp16 intermediates + v_dot2_f32_f16, 16-row sub-phases, register prefetch
// pipeline, 8 barriers. O aliases Q (same-row only). XCD batch swizzle.
// ---------------------------------------------------------------------------
#define KVSTRIDE 520
template <typename IT>
__global__ __launch_bounds__(256, 7) void attn_kernel(const ushort_t* Q,
                                                      const ushort_t* __restrict__ K,
                                                      const ushort_t* __restrict__ V,
                                                      const IT* __restrict__ idx,
                                                      const float* __restrict__ wts,
                                                      ushort_t* O) {
    __shared__ uint32_t qs[16][20];         // raw fp16 pairs; row=h*2+half
    __shared__ ushort_t kvs[16][KVSTRIDE];  // 16-row staging buffer
    __shared__ float ps[H_][KNN_];
    __shared__ int idxs[KNN_];
    __shared__ float ws[KNN_];

    const int t = threadIdx.x;
    const int id = blockIdx.x;
    const int xcd = id & 7;
    const int slot = id >> 3;
    const int b = xcd >> 2;
    const int bq = b * HW_ + (xcd & 3) * 1024 + slot;
    const size_t qoff = (size_t)bq * C_;

    // Q is fp16: raw pair copy, no conversion
    qs[t >> 4][t & 15] = *(const uint32_t*)(Q + qoff + 2 * t);
    if (t < KNN_) {
        idxs[t] = (int)idx[(size_t)bq * KNN_ + t];
        ws[t] = wts[(size_t)bq * KNN_ + t];
    }
    __syncthreads();  // (1) idxs/ws/qs ready

    const ushort_t* Kbase = K + (size_t)b * NTGT_ * C_;
    const ushort_t* Vbase = V + (size_t)b * NTGT_ * C_;
    const int prow = t >> 4;          // staging row 0..15 (16 lanes/row)
    const int pcol = (t & 15) * 8;    // element offset; +j*128 covers 512

    const int h = t >> 5;
    const int l5 = t & 31;
    const int nl = l5 & 15;
    const int half = l5 >> 4;
    const int koff = h * 64 + half * 32;

    uint4 r0, r1, r2, r3;
    // K rows 0-15 -> regs -> LDS
    {
        const ushort_t* p = Kbase + (size_t)idxs[prow] * C_ + pcol;
        r0 = *(const uint4*)(p);       r1 = *(const uint4*)(p + 128);
        r2 = *(const uint4*)(p + 256); r3 = *(const uint4*)(p + 384);
    }
    // hoist Q fragment into regs (LDS; independent counter from globals)
    const int qrow = h * 2 + half;
    uint4 q0 = *(const uint4*)&qs[qrow][0];
    uint4 q1 = *(const uint4*)&qs[qrow][4];
    uint4 q2 = *(const uint4*)&qs[qrow][8];
    uint4 q3 = *(const uint4*)&qs[qrow][12];

    *(uint4*)&kvs[prow][pcol + 0]   = r0;
    *(uint4*)&kvs[prow][pcol + 128] = r1;
    *(uint4*)&kvs[prow][pcol + 256] = r2;
    *(uint4*)&kvs[prow][pcol + 384] = r3;
    // issue K rows 16-31 early (latency hides under dot phase A)
    {
        const ushort_t* p = Kbase + (size_t)idxs[prow + 16] * C_ + pcol;
        r0 = *(const uint4*)(p);       r1 = *(const uint4*)(p + 128);
        r2 = *(const uint4*)(p + 256); r3 = *(const uint4*)(p + 384);
    }
    __syncthreads();  // (2) K rows 0-15 staged

    float l0, l1;
    {
        uint4 kv0 = *(const uint4*)&kvs[nl][koff + 0];
        uint4 kv1 = *(const uint4*)&kvs[nl][koff + 8];
        uint4 kv2 = *(const uint4*)&kvs[nl][koff + 16];
        uint4 kv3 = *(const uint4*)&kvs[nl][koff + 24];
        float da = 0.f, db = 0.f;
        da = dot2acc(kv0.x, q0.x, da); da = dot2acc(kv0.y, q0.y, da);
        da = dot2acc(kv0.z, q0.z, da); da = dot2acc(kv0.w, q0.w, da);
        db = dot2acc(kv1.x, q1.x, db); db = dot2acc(kv1.y, q1.y, db);
        db = dot2acc(kv1.z, q1.z, db); db = dot2acc(kv1.w, q1.w, db);
        da = dot2acc(kv2.x, q2.x, da); da = dot2acc(kv2.y, q2.y, da);
        da = dot2acc(kv2.z, q2.z, da); da = dot2acc(kv2.w, q2.w, da);
        db = dot2acc(kv3.x, q3.x, db); db = dot2acc(kv3.y, q3.y, db);
        db = dot2acc(kv3.z, q3.z, db); db = dot2acc(kv3.w, q3.w, db);
        float dot = da + db;
        dot += __shfl_xor(dot, 16);   // combine halves: full 64-elem dot
        l0 = dot * 0.125f + ws[nl];
    }
    __syncthreads();  // (3) K-A reads complete
    // publish K rows 16-31; issue V rows 0-15
    *(uint4*)&kvs[prow][pcol + 0]   = r0;
    *(uint4*)&kvs[prow][pcol + 128] = r1;
    *(uint4*)&kvs[prow][pcol + 256] = r2;
    *(uint4*)&kvs[prow][pcol + 384] = r3;
    {
        const ushort_t* p = Vbase + (size_t)idxs[prow] * C_ + pcol;
        r0 = *(const uint4*)(p);       r1 = *(const uint4*)(p + 128);
        r2 = *(const uint4*)(p + 256); r3 = *(const uint4*)(p + 384);
    }
    __syncthreads();  // (4) K rows 16-31 staged
    {
        uint4 kv0 = *(const uint4*)&kvs[nl][koff + 0];
        uint4 kv1 = *(const uint4*)&kvs[nl][koff + 8];
        uint4 kv2 = *(const uint4*)&kvs[nl][koff + 16];
        uint4 kv3 = *(const uint4*)&kvs[nl][koff + 24];
        float da = 0.f, db = 0.f;
        da = dot2acc(kv0.x, q0.x, da); da = dot2acc(kv0.y, q0.y, da);
        da = dot2acc(kv0.z, q0.z, da); da = dot2acc(kv0.w, q0.w, da);
        db = dot2acc(kv1.x, q1.x, db); db = dot2acc(kv1.y, q1.y, db);
        db = dot2acc(kv1.z, q1.z, db); db = dot2acc(kv1.w, q1.w, db);
        da = dot2acc(kv2.x, q2.x, da); da = dot2acc(kv2.y, q2.y, da);
        da = dot2acc(kv2.z, q2.z, da); da = dot2acc(kv2.w, q2.w, da);
        db = dot2acc(kv3.x, q3.x, db); db = dot2acc(kv3.y, q3.y, db);
        db = dot2acc(kv3.z, q3.z, db); db = dot2acc(kv3.w, q3.w, db);
        float dot = da + db;
        dot += __shfl_xor(dot, 16);
        l1 = dot * 0.125f + ws[nl + 16];
    }
    // softmax over 32 logits; each n present in exactly 2 lanes of the group
    {
        float m = fmaxf(l0, l1);
#pragma unroll
        for (int o = 16; o > 0; o >>= 1) m = fmaxf(m, __shfl_xor(m, o));
        float e0 = __expf(l0 - m), e1 = __expf(l1 - m);
        float s = e0 + e1;
#pragma unroll
        for (int o = 16; o > 0; o >>= 1) s += __shfl_xor(s, o);
        const float inv = 2.0f / s;   // duplicates double-count: exact /2
        ps[h][nl] = e0 * inv;         // duplicate lanes write same value
        ps[h][nl + 16] = e1 * inv;
    }
    __syncthreads();  // (5) K-B reads + ps writes complete
    // publish V rows 0-15; issue V rows 16-31
    *(uint4*)&kvs[prow][pcol + 0]   = r0;
    *(uint4*)&kvs[prow][pcol + 128] = r1;
    *(uint4*)&kvs[prow][pcol + 256] = r2;
    *(uint4*)&kvs[prow][pcol + 384] = r3;
    {
        const ushort_t* p = Vbase + (size_t)idxs[prow + 16] * C_ + pcol;
        r0 = *(const uint4*)(p);       r1 = *(const uint4*)(p + 128);
        r2 = *(const uint4*)(p + 256); r3 = *(const uint4*)(p + 384);
    }
    __syncthreads();  // (6) V rows 0-15 staged

    const int d2 = l5 * 2;
    float a0 = 0.f, a1 = 0.f;
#pragma unroll
    for (int nn = 0; nn < 16; ++nn) {
        uint32_t vv = *(const uint32_t*)&kvs[nn][h * DH_ + d2];
        float p = ps[h][nn];
        a0 = fmaf(p, h2f((ushort_t)(vv & 0xffffu)), a0);
        a1 = fmaf(p, h2f((ushort_t)(vv >> 16)), a1);
    }
    __syncthreads();  // (7) V-A reads complete
    *(uint4*)&kvs[prow][pcol + 0]   = r0;
    *(uint4*)&kvs[prow][pcol + 128] = r1;
    *(uint4*)&kvs[prow][pcol + 256] = r2;
    *(uint4*)&kvs[prow][pcol + 384] = r3;
    __syncthreads();  // (8) V rows 16-31 staged
#pragma unroll
    for (int nn = 0; nn < 16; ++nn) {
        uint32_t vv = *(const uint32_t*)&kvs[nn][h * DH_ + d2];
        float p = ps[h][nn + 16];
        a0 = fmaf(p, h2f((ushort_t)(vv & 0xffffu)), a0);
        a1 = fmaf(p, h2f((ushort_t)(vv >> 16)), a1);
    }
    *(uint32_t*)(O + qoff + h * DH_ + d2) = pkh(a0, a1);
}

// ---------------------------------------------------------------------------
static int elem_bytes(const void* p, size_t n, int dflt) {
    size_t sz = 0;
    hipError_t err = hipPointerGetAttribute(
        &sz, HIP_POINTER_ATTRIBUTE_RANGE_SIZE, (hipDeviceptr_t)(uintptr_t)p);
    if (err == hipSuccess && sz >= n && (sz % n) == 0) {
        size_t b = sz / n;
        if (b == 2 || b == 4 || b == 8) return (int)b;
    }
    return dflt;
}

extern "C" void kernel_launch(void* const* d_in, const int* in_sizes, int n_in,
                              void* d_out, int out_size, void* d_ws, size_t ws_size,
                              hipStream_t stream) {
    const float* src  = (const float*)d_in[0];
    const float* tgt  = (const float*)d_in[1];
    const void*  idxp = d_in[2];
    const float* wtp  = (const float*)d_in[3];
    float* Wq = (float*)d_in[4];  const float* bq = (const float*)d_in[5];
    float* Wk = (float*)d_in[6];  const float* bk = (const float*)d_in[7];
    float* Wv = (float*)d_in[8];  const float* bv = (const float*)d_in[9];
    float* Wo = (float*)d_in[10]; const float* bo = (const float*)d_in[11];

    const size_t NELEM = (size_t)M_ * C_;          // 4,194,304
    const size_t WELEM = (size_t)C_ * C_;          // 262,144
    const size_t NIDX  = (size_t)B_ * HW_ * KNN_;

    const int ib = elem_bytes(idxp, NIDX, 4);
    const int ob = elem_bytes(d_out, NELEM, 4);

    dim3 blk(256);

    // ws: Q fp16 [0,8MB) | K fp16 [8,16MB) | optional fp16 Wt x4 [16,18MB).
    // V fp16 in d_out (consumed by attn before gemm_o overwrites);
    // attn output aliases Q.
    ushort_t* Qb = (ushort_t*)d_ws;
    ushort_t* Kb = Qb + NELEM;
    ushort_t* Vb = (ushort_t*)d_out;
    ushort_t* Ob = Qb;

    const bool wfit = ws_size >= (2 * NELEM + 4 * WELEM) * sizeof(ushort_t);

    if (wfit) {
        // fp16 transposed weights in ws tail (no input mutation)
        ushort_t* T = Kb + NELEM;
        ushort_t* WtQ = T;
        ushort_t* WtK = T + WELEM;
        ushort_t* WtV = T + 2 * WELEM;
        ushort_t* WtO = T + 3 * WELEM;

        transpose_cvt4<<<dim3(16, 16, 4), blk, 0, stream>>>(
            Wq, Wk, Wv, Wo, WtQ, WtK, WtV, WtO);

        gemm_qkv<float, ushort_t><<<dim3(768), blk, 0, stream>>>(
            src, tgt, WtQ, WtK, WtV, bq, bk, bv, Qb, Kb, Vb);

        if (ib == 8)
            attn_kernel<long long><<<dim3(B_ * HW_), blk, 0, stream>>>(
                Qb, Kb, Vb, (const long long*)idxp, wtp, Ob);
        else
            attn_kernel<int><<<dim3(B_ * HW_), blk, 0, stream>>>(
                Qb, Kb, Vb, (const int*)idxp, wtp, Ob);

        if (ob == 2)
            gemm_o_gl<ushort_t, true><<<dim3(512), blk, 0, stream>>>(
                Ob, WtO, bo, (ushort_t*)d_out);
        else
            gemm_o_gl<float, false><<<dim3(512), blk, 0, stream>>>(
                Ob, WtO, bo, (float*)d_out);
    } else {
        // fallback: in-place fp32 transpose, fp32-B GEMMs (reg-staging body)
        transpose_inplace4_f32<<<dim3(136, 4), blk, 0, stream>>>(Wq, Wk, Wv, Wo);

        gemm_qkv<float, float><<<dim3(768), blk, 0, stream>>>(
            src, tgt, Wq, Wk, Wv, bq, bk, bv, Qb, Kb, Vb);

        if (ib == 8)
            attn_kernel<long long><<<dim3(B_ * HW_), blk, 0, stream>>>(
                Qb, Kb, Vb, (const long long*)idxp, wtp, Ob);
        else
            attn_kernel<int><<<dim3(B_ * HW_), blk, 0, stream>>>(
                Qb, Kb, Vb, (const int*)idxp, wtp, Ob);

        if (ob == 2)
            gemm_o<float, ushort_t, true><<<dim3(512), blk, 0, stream>>>(
                Ob, Wo, bo, (ushort_t*)d_out);
        else
            gemm_o<float, float, false><<<dim3(512), blk, 0, stream>>>(
                Ob, Wo, bo, (float*)d_out);
    }
}